// Round 1
// baseline (124.250 us; speedup 1.0000x reference)
//
#include <hip/hip_runtime.h>
#include <math.h>

// QuixerCore: N_QUBITS=11 (DIM=2048), N_TOKENS=32, D_MODEL=512, DEGREE=2,
// N_LAYERS=1, N_PQC=44, L_limit=4.
//
// Key simplification (faithful to reference): only RY gates act (CRX blocks are
// no-ops in the source). RY's on different qubits commute; RY's on the same
// qubit compose additively. So each token unitary U_t = ⊗_q RY(ang[q]+ang[22+q])
// and is applied as 11 butterfly sweeps over the 2048-dim complex state.
// Same for U_ff with ff_params.

#define DIMQ 2048
#define NQ 11
#define NT 1024   // threads per block (2 state elements per thread)

__device__ __forceinline__ float block_reduce_sum(float v, float* red) {
    const int lane = threadIdx.x & 63;
    const int wid  = threadIdx.x >> 6;
    #pragma unroll
    for (int off = 32; off > 0; off >>= 1) v += __shfl_down(v, off);
    if (lane == 0) red[wid] = v;
    __syncthreads();
    float r = 0.f;
    if (wid == 0) {
        r = (lane < 16) ? red[lane] : 0.f;   // 16 waves in a 1024-thread block
        #pragma unroll
        for (int off = 32; off > 0; off >>= 1) r += __shfl_down(r, off);
        if (lane == 0) red[0] = r;
    }
    __syncthreads();
    float out = red[0];
    __syncthreads();   // protect red[] for the next call
    return out;
}

__global__ __launch_bounds__(NT) void quixer_kernel(
    const float* __restrict__ emb,    // [32,512] tokens_emb
    const float* __restrict__ Wang,   // [44,512] W_angles
    const float* __restrict__ bang,   // [44]     b_angles
    const float* __restrict__ qc,     // [3]      qsvt_coeffs
    const float* __restrict__ lre,    // [32]     lcu_re
    const float* __restrict__ lim,    // [32]     lcu_im
    const float* __restrict__ ffp,    // [44]     ff_params
    float* __restrict__ out)          // [33]
{
    __shared__ float mr[DIMQ], mi[DIMQ];   // monomial / working state
    __shared__ float tr[DIMQ], ti[DIMQ];   // scratch for U_t application
    __shared__ float tc[4][NQ], ts[4][NQ]; // cos/sin(phi/2) per token,qubit
    __shared__ float ffc[NQ], ffs[NQ];
    __shared__ float lcur[4], lcui[4];     // normalized LCU coeffs (first 4)
    __shared__ float red[16];

    const int tid  = threadIdx.x;
    const int lane = tid & 63;
    const int wid  = tid >> 6;
    const int i0 = tid, i1 = tid + NT;

    // ---- Phase A: angles = emb[:4] @ W^T + b ; combine RY blocks 0 and 2 ----
    // 44 jobs (t<4, q<11), one wave per job, looped over 16 waves.
    for (int j = wid; j < 44; j += 16) {
        const int t = j / NQ, q = j - t * NQ;
        const float* e  = emb + t * 512;
        const float* w0 = Wang + q * 512;
        const float* w1 = Wang + (q + 22) * 512;
        float a = 0.f;
        for (int d = lane; d < 512; d += 64) a += e[d] * (w0[d] + w1[d]);
        #pragma unroll
        for (int off = 32; off > 0; off >>= 1) a += __shfl_down(a, off);
        if (lane == 0) {
            const float phi = a + bang[q] + bang[q + 22];
            tc[t][q] = cosf(0.5f * phi);
            ts[t][q] = sinf(0.5f * phi);
        }
    }
    if (tid < NQ) {
        const float phi = ffp[tid] + ffp[tid + 22];
        ffc[tid] = cosf(0.5f * phi);
        ffs[tid] = sinf(0.5f * phi);
    }
    if (tid == 0) {
        float s = 0.f;
        for (int t = 0; t < 32; t++) s += sqrtf(lre[t]*lre[t] + lim[t]*lim[t]);
        const float denom = fmaxf(s, 1e-8f);
        for (int t = 0; t < 4; t++) { lcur[t] = lre[t]/denom; lcui[t] = lim[t]/denom; }
    }

    // ---- init: mono = e0, acc = qc[0]*e0 (acc in registers, 2 elems/thread) ----
    mr[i0] = (i0 == 0) ? 1.f : 0.f;  mi[i0] = 0.f;
    mr[i1] = 0.f;                    mi[i1] = 0.f;
    float ar0 = (i0 == 0) ? qc[0] : 0.f, ai0 = 0.f;
    float ar1 = 0.f, ai1 = 0.f;
    __syncthreads();

    // ---- Phase C: QSVT monomial recursion, k = 1..DEGREE ----
    for (int k = 1; k <= 2; k++) {
        // _apply_lcu small-norm branch (faithful). For norm >= 1e-8 the
        // divide-by-norm and multiply-by-norm cancel (linear map), so skip both.
        float nsq = mr[i0]*mr[i0] + mi[i0]*mi[i0] + mr[i1]*mr[i1] + mi[i1]*mi[i1];
        nsq = block_reduce_sum(nsq, red);
        if (sqrtf(nsq) < 1e-8f) {
            mr[i0] = (i0 == 0) ? 1.f : 0.f;  mi[i0] = 0.f;
            mr[i1] = 0.f;                    mi[i1] = 0.f;
            __syncthreads();
        }

        float lr0 = 0.f, li0 = 0.f, lr1 = 0.f, li1 = 0.f;  // lcu sum (regs)
        for (int t = 0; t < 4; t++) {
            // qubit 0 sweep fused with mono->tmp copy: pair is exactly (i0,i1)
            {
                const float c = tc[t][0], s = ts[t][0];
                const float axr = mr[i0], axi = mi[i0], bxr = mr[i1], bxi = mi[i1];
                tr[i0] = c*axr - s*bxr;  ti[i0] = c*axi - s*bxi;
                tr[i1] = s*axr + c*bxr;  ti[i1] = s*axi + c*bxi;
            }
            __syncthreads();
            for (int q = 1; q < NQ; q++) {
                const int sh  = 10 - q;
                const int stp = 1 << sh;
                const int a = ((tid >> sh) << (sh + 1)) | (tid & (stp - 1));
                const int b = a + stp;
                const float c = tc[t][q], s = ts[t][q];
                const float axr = tr[a], axi = ti[a], bxr = tr[b], bxi = ti[b];
                tr[a] = c*axr - s*bxr;  ti[a] = c*axi - s*bxi;
                tr[b] = s*axr + c*bxr;  ti[b] = s*axi + c*bxi;
                __syncthreads();
            }
            // lsum += lcu[t] * (U_t mono)   (own elements only -> no race)
            const float cr = lcur[t], ci = lcui[t];
            lr0 += cr*tr[i0] - ci*ti[i0];  li0 += cr*ti[i0] + ci*tr[i0];
            lr1 += cr*tr[i1] - ci*ti[i1];  li1 += cr*ti[i1] + ci*tr[i1];
        }
        // mono = lsum ; acc += qc[k] * lsum
        mr[i0] = lr0; mi[i0] = li0; mr[i1] = lr1; mi[i1] = li1;
        const float qk = qc[k];
        ar0 += qk*lr0; ai0 += qk*li0; ar1 += qk*lr1; ai1 += qk*li1;
        __syncthreads();
    }

    // ---- Phase D: acc /= clip(|c0|+|c1|+|c2|); normalize; apply U_ff ----
    const float pn = fmaxf(fabsf(qc[0]) + fabsf(qc[1]) + fabsf(qc[2]), 1e-8f);
    ar0 /= pn; ai0 /= pn; ar1 /= pn; ai1 /= pn;
    float snsq = ar0*ar0 + ai0*ai0 + ar1*ar1 + ai1*ai1;
    snsq = block_reduce_sum(snsq, red);
    const float sn = sqrtf(snsq);
    if (sn < 1e-8f) {
        mr[i0] = (i0 == 0) ? 1.f : 0.f;  mi[i0] = 0.f;
        mr[i1] = 0.f;                    mi[i1] = 0.f;
    } else {
        const float inv = 1.f / sn;
        mr[i0] = ar0*inv; mi[i0] = ai0*inv; mr[i1] = ar1*inv; mi[i1] = ai1*inv;
    }
    __syncthreads();
    for (int q = 0; q < NQ; q++) {
        const int sh  = 10 - q;
        const int stp = 1 << sh;
        const int a = ((tid >> sh) << (sh + 1)) | (tid & (stp - 1));
        const int b = a + stp;
        const float c = ffc[q], s = ffs[q];
        const float axr = mr[a], axi = mi[a], bxr = mr[b], bxi = mi[b];
        mr[a] = c*axr - s*bxr;  mi[a] = c*axi - s*bxi;
        mr[b] = s*axr + c*bxr;  mi[b] = s*axi + c*bxi;
        __syncthreads();
    }

    // ---- Phase E: Pauli expectations, order per qubit: X, Y, Z ----
    for (int q = 0; q < NQ; q++) {
        const int sh  = 10 - q;
        const int stp = 1 << sh;
        float px = 0.f, py = 0.f, pz = 0.f;
        #pragma unroll
        for (int e = 0; e < 2; e++) {
            const int i   = tid + e * NT;
            const int bit = (i >> sh) & 1;
            const int j   = i ^ stp;
            const float are = mr[i], aim = mi[i], bre = mr[j], bim = mi[j];
            px += are*bre + aim*bim;                         // Re(conj(a)*b)
            const float imz = are*bim - aim*bre;             // Im(conj(a)*b)
            py += bit ? -imz : imz;
            const float p2 = are*are + aim*aim;
            pz += bit ? -p2 : p2;
        }
        px = block_reduce_sum(px, red);
        py = block_reduce_sum(py, red);
        pz = block_reduce_sum(pz, red);
        if (tid == 0) {
            out[3*q + 0] = px;
            out[3*q + 1] = py;
            out[3*q + 2] = pz;
        }
    }
}

extern "C" void kernel_launch(void* const* d_in, const int* in_sizes, int n_in,
                              void* d_out, int out_size, void* d_ws, size_t ws_size,
                              hipStream_t stream) {
    quixer_kernel<<<1, NT, 0, stream>>>(
        (const float*)d_in[0],  // tokens_emb [32,512]
        (const float*)d_in[1],  // W_angles   [44,512]
        (const float*)d_in[2],  // b_angles   [44]
        (const float*)d_in[3],  // qsvt_coeffs[3]
        (const float*)d_in[4],  // lcu_re     [32]
        (const float*)d_in[5],  // lcu_im     [32]
        (const float*)d_in[6],  // ff_params  [44]
        (float*)d_out);         // [33]
}

// Round 2
// 117.771 us; speedup vs baseline: 1.0550x; 1.0550x over previous
//
#include <hip/hip_runtime.h>
#include <math.h>

// QuixerCore on gfx950 — register-resident statevector version.
//
// Math (faithful to reference): only RY gates act (CRX helper is a no-op in
// the source). RYs on distinct qubits commute; same-qubit RYs compose
// additively, so token unitary U_t = ⊗_q RY(ang[q]+ang[22+q]).
//
// Layout: state index i = (r<<6)|lane; r = register index (32 complex/lane),
// lane = low 6 bits. Qubit q has stride 2^(10-q):
//   q in [0,4]  -> register-bit butterfly, mask 1<<(4-q)   (pure VALU)
//   q in [5,10] -> lane-bit butterfly via __shfl_xor, mask 1<<(10-q)
// 4 waves (256 threads), wave t owns token t. Only cross-wave exchange is the
// LCU sum: 64KB LDS (4 regions), 2 barriers per QSVT step, ~5 barriers total.

#define NQ 11

__device__ __forceinline__ float wave_allreduce(float v) {
#pragma unroll
    for (int m = 1; m < 64; m <<= 1) v += __shfl_xor(v, m);
    return v;
}

// Butterfly stage on register-bit qubit q (q in [0,4])
#define REG_STAGE(q) do {                                                     \
    const int m_ = 1 << (4 - (q));                                            \
    const float cq_ = C[q], sq_ = S[q];                                       \
    _Pragma("unroll")                                                         \
    for (int r_ = 0; r_ < 32; r_++) {                                         \
        if (!(r_ & m_)) {                                                     \
            const int b_ = r_ | m_;                                           \
            const float arr_ = sr[r_], aii_ = si[r_];                         \
            const float brr_ = sr[b_], bii_ = si[b_];                         \
            sr[r_] = cq_ * arr_ - sq_ * brr_;                                 \
            si[r_] = cq_ * aii_ - sq_ * bii_;                                 \
            sr[b_] = sq_ * arr_ + cq_ * brr_;                                 \
            si[b_] = sq_ * aii_ + cq_ * bii_;                                 \
        }                                                                     \
    }                                                                         \
} while (0)

// Butterfly stage on lane-bit qubit q (q in [5,10]).
// new = c*x + (bit ? +s : -s) * partner   (RY is real, same for re/im)
#define LANE_STAGE(q) do {                                                    \
    const int m_ = 1 << (10 - (q));                                           \
    const float cq_ = C[q];                                                   \
    const float ssn_ = (lane & m_) ? S[q] : -S[q];                            \
    _Pragma("unroll")                                                         \
    for (int r_ = 0; r_ < 32; r_++) {                                         \
        const float pr_ = __shfl_xor(sr[r_], m_);                             \
        const float pi_ = __shfl_xor(si[r_], m_);                             \
        sr[r_] = cq_ * sr[r_] + ssn_ * pr_;                                   \
        si[r_] = cq_ * si[r_] + ssn_ * pi_;                                   \
    }                                                                         \
} while (0)

#define APPLY_ALL() do {                                                      \
    REG_STAGE(0); REG_STAGE(1); REG_STAGE(2); REG_STAGE(3); REG_STAGE(4);     \
    LANE_STAGE(5); LANE_STAGE(6); LANE_STAGE(7); LANE_STAGE(8);               \
    LANE_STAGE(9); LANE_STAGE(10);                                            \
} while (0)

// Pauli X/Y/Z expectations for a register-bit qubit q (q in [0,4])
#define MEASURE_REG(q) do {                                                   \
    const int m_ = 1 << (4 - (q));                                            \
    float px_ = 0.f, py_ = 0.f, pz_ = 0.f;                                    \
    _Pragma("unroll")                                                         \
    for (int r_ = 0; r_ < 32; r_++) {                                         \
        const int j_ = r_ ^ m_;                                               \
        px_ += sr[r_] * sr[j_] + si[r_] * si[j_];                             \
        const float imz_ = sr[r_] * si[j_] - si[r_] * sr[j_];                 \
        py_ += (r_ & m_) ? -imz_ : imz_;                                      \
        const float p2_ = sr[r_] * sr[r_] + si[r_] * si[r_];                  \
        pz_ += (r_ & m_) ? -p2_ : p2_;                                        \
    }                                                                         \
    px_ = wave_allreduce(px_);                                                \
    py_ = wave_allreduce(py_);                                                \
    pz_ = wave_allreduce(pz_);                                                \
    if (lane == 0) {                                                          \
        out[3 * (q) + 0] = px_;                                               \
        out[3 * (q) + 1] = py_;                                               \
        out[3 * (q) + 2] = pz_;                                               \
    }                                                                         \
} while (0)

// Pauli X/Y/Z expectations for a lane-bit qubit q (q in [5,10])
#define MEASURE_LANE(q) do {                                                  \
    const int m_ = 1 << (10 - (q));                                           \
    const int bit_ = lane & m_;                                               \
    float px_ = 0.f, py_ = 0.f, pz_ = 0.f;                                    \
    _Pragma("unroll")                                                         \
    for (int r_ = 0; r_ < 32; r_++) {                                         \
        const float pr_ = __shfl_xor(sr[r_], m_);                             \
        const float pi_ = __shfl_xor(si[r_], m_);                             \
        px_ += sr[r_] * pr_ + si[r_] * pi_;                                   \
        const float imz_ = sr[r_] * pi_ - si[r_] * pr_;                       \
        py_ += bit_ ? -imz_ : imz_;                                           \
        const float p2_ = sr[r_] * sr[r_] + si[r_] * si[r_];                  \
        pz_ += bit_ ? -p2_ : p2_;                                             \
    }                                                                         \
    px_ = wave_allreduce(px_);                                                \
    py_ = wave_allreduce(py_);                                                \
    pz_ = wave_allreduce(pz_);                                                \
    if (lane == 0) {                                                          \
        out[3 * (q) + 0] = px_;                                               \
        out[3 * (q) + 1] = py_;                                               \
        out[3 * (q) + 2] = pz_;                                               \
    }                                                                         \
} while (0)

__global__ __launch_bounds__(256, 1) void quixer_kernel(
    const float* __restrict__ emb,    // [32,512] tokens_emb
    const float* __restrict__ Wang,   // [44,512] W_angles
    const float* __restrict__ bang,   // [44]     b_angles
    const float* __restrict__ qc,     // [3]      qsvt_coeffs
    const float* __restrict__ lre,    // [32]     lcu_re
    const float* __restrict__ lim,    // [32]     lcu_im
    const float* __restrict__ ffp,    // [44]     ff_params
    float* __restrict__ out)          // [33]
{
    __shared__ float2 ex[4][2048];    // 64 KB: per-token scaled U_t|mono>

    const int tid  = threadIdx.x;
    const int w    = tid >> 6;        // wave id == token id (0..3)
    const int lane = tid & 63;

    // ---- Phase A: this wave's token angles -> C[q],S[q] (wave-uniform) ----
    float C[NQ], S[NQ];
    {
        const float* e = emb + w * 512;
        float ev[8];
#pragma unroll
        for (int j = 0; j < 8; j++) ev[j] = e[lane + 64 * j];
#pragma unroll
        for (int q = 0; q < NQ; q++) {
            const float* w0 = Wang + q * 512;
            const float* w1 = Wang + (q + 22) * 512;
            float a = 0.f;
#pragma unroll
            for (int j = 0; j < 8; j++) {
                const int d = lane + 64 * j;
                a += ev[j] * (w0[d] + w1[d]);
            }
            a = wave_allreduce(a);
            const float phi = a + bang[q] + bang[q + 22];
            C[q] = cosf(0.5f * phi);
            S[q] = sinf(0.5f * phi);
        }
    }

    // ---- LCU coeffs (wave-redundant; each wave needs only its own token) ----
    float lr, li;
    {
        float av = 0.f;
        if (lane < 32) {
            const float re = lre[lane], iv = lim[lane];
            av = sqrtf(re * re + iv * iv);
        }
        const float denom = fmaxf(wave_allreduce(av), 1e-8f);
        lr = lre[w] / denom;
        li = lim[w] / denom;
    }
    const float qc0 = qc[0], qc1 = qc[1], qc2 = qc[2];

    // ---- init: mono = e0, acc = qc0*e0 (each wave holds full copies) ----
    float sr[32], si[32], ar[32], ai[32];
#pragma unroll
    for (int r = 0; r < 32; r++) { sr[r] = 0.f; si[r] = 0.f; ar[r] = 0.f; ai[r] = 0.f; }
    if (lane == 0) { sr[0] = 1.f; ar[0] = qc0; }

    // ---- QSVT monomial recursion, k = 1..2 ----
#pragma unroll
    for (int k = 1; k <= 2; k++) {
        // faithful small-norm branch of _apply_lcu (norm>=1e-8: scale cancels)
        float nsq = 0.f;
#pragma unroll
        for (int r = 0; r < 32; r++) nsq += sr[r] * sr[r] + si[r] * si[r];
        nsq = wave_allreduce(nsq);
        if (sqrtf(nsq) < 1e-8f) {
#pragma unroll
            for (int r = 0; r < 32; r++) { sr[r] = 0.f; si[r] = 0.f; }
            if (lane == 0) sr[0] = 1.f;
        }

        // this wave applies its token's unitary in-register
        APPLY_ALL();

        // write lcu[w] * (U_w mono) to this wave's LDS region
#pragma unroll
        for (int r = 0; r < 32; r++) {
            const int i = (r << 6) | lane;
            ex[w][i] = make_float2(lr * sr[r] - li * si[r],
                                   lr * si[r] + li * sr[r]);
        }
        __syncthreads();

        // mono = sum over 4 token regions; acc += qc[k] * mono
#pragma unroll
        for (int r = 0; r < 32; r++) {
            const int i = (r << 6) | lane;
            const float2 v0 = ex[0][i], v1 = ex[1][i], v2 = ex[2][i], v3 = ex[3][i];
            sr[r] = v0.x + v1.x + v2.x + v3.x;
            si[r] = v0.y + v1.y + v2.y + v3.y;
        }
        const float qk = (k == 1) ? qc1 : qc2;
#pragma unroll
        for (int r = 0; r < 32; r++) { ar[r] += qk * sr[r]; ai[r] += qk * si[r]; }
        __syncthreads();   // regions reusable next iteration
    }

    // ---- Phase D: acc /= clip(poly_norm); normalize; apply U_ff ----
    const float pn = fmaxf(fabsf(qc0) + fabsf(qc1) + fabsf(qc2), 1e-8f);
    float snsq = 0.f;
#pragma unroll
    for (int r = 0; r < 32; r++) {
        ar[r] /= pn; ai[r] /= pn;
        snsq += ar[r] * ar[r] + ai[r] * ai[r];
    }
    snsq = wave_allreduce(snsq);
    const float sn = sqrtf(snsq);
    if (sn < 1e-8f) {
#pragma unroll
        for (int r = 0; r < 32; r++) { sr[r] = 0.f; si[r] = 0.f; }
        if (lane == 0) sr[0] = 1.f;
    } else {
        const float inv = 1.f / sn;
#pragma unroll
        for (int r = 0; r < 32; r++) { sr[r] = ar[r] * inv; si[r] = ai[r] * inv; }
    }

    // ff coefficients overwrite C/S (all waves redundantly)
#pragma unroll
    for (int q = 0; q < NQ; q++) {
        const float phi = ffp[q] + ffp[q + 22];
        C[q] = cosf(0.5f * phi);
        S[q] = sinf(0.5f * phi);
    }
    APPLY_ALL();   // every wave now holds the final state

    // ---- Phase E: Pauli expectations, qubits split across waves ----
    switch (w) {
        case 0: MEASURE_REG(0); MEASURE_REG(4); MEASURE_LANE(8);  break;
        case 1: MEASURE_REG(1); MEASURE_LANE(5); MEASURE_LANE(9); break;
        case 2: MEASURE_REG(2); MEASURE_LANE(6); MEASURE_LANE(10); break;
        case 3: MEASURE_REG(3); MEASURE_LANE(7); break;
    }
}

extern "C" void kernel_launch(void* const* d_in, const int* in_sizes, int n_in,
                              void* d_out, int out_size, void* d_ws, size_t ws_size,
                              hipStream_t stream) {
    quixer_kernel<<<1, 256, 0, stream>>>(
        (const float*)d_in[0],  // tokens_emb [32,512]
        (const float*)d_in[1],  // W_angles   [44,512]
        (const float*)d_in[2],  // b_angles   [44]
        (const float*)d_in[3],  // qsvt_coeffs[3]
        (const float*)d_in[4],  // lcu_re     [32]
        (const float*)d_in[5],  // lcu_im     [32]
        (const float*)d_in[6],  // ff_params  [44]
        (float*)d_out);         // [33]
}

// Round 3
// 82.084 us; speedup vs baseline: 1.5137x; 1.4348x over previous
//
#include <hip/hip_runtime.h>
#include <math.h>

// QuixerCore on gfx950 — register-resident statevector, DPP + LDS-transpose.
//
// Math (faithful): only RY gates act; same-qubit RYs compose additively, so
// U_t = ⊗_q RY(ang[q]+ang[22+q]).
//
// Layout A: lane L holds sr[r] = state[(r<<6)|L]  -> reg bits = qubits 0..4
// Layout B: lane L holds sr[r'] = state[(L<<5)|r'] -> reg bits = qubits 6..10,
//           qubit 5 = lane bit 0 (DPP quad_perm), qubits 0..4 = lane bits 5..1.
// Transpose A<->B: 32 ds_write_b64 + 32 ds_read_b64 per wave in a wave-private
// 16KB LDS region with XOR swizzle p = i ^ ((i>>6)&15) -> both access
// patterns sit at the b64 bank floor (4 cycles). LDS ops within a wave
// complete in order, so no __syncthreads is needed for the transpose.
// All reductions use DPP row_shr/row_bcast (VALU) — zero ds_bpermute.

#define NQ 11

template<int CTRL>
__device__ __forceinline__ float dpp_mov(float x) {
    return __int_as_float(__builtin_amdgcn_update_dpp(
        0, __float_as_int(x), CTRL, 0xF, 0xF, false));
}

// full-wave sum, result broadcast (uniform) to all lanes
__device__ __forceinline__ float wave_sum(float v) {
    v += dpp_mov<0x111>(v);   // row_shr:1
    v += dpp_mov<0x112>(v);   // row_shr:2
    v += dpp_mov<0x114>(v);   // row_shr:4
    v += dpp_mov<0x118>(v);   // row_shr:8
    v += dpp_mov<0x142>(v);   // row_bcast:15
    v += dpp_mov<0x143>(v);   // row_bcast:31
    return __int_as_float(__builtin_amdgcn_readlane(__float_as_int(v), 63));
}

// RY butterfly on register-bit with mask m, coefficients C[q],S[q]
#define REG_STAGE(q, m) do {                                                  \
    const float cq_ = C[q], sq_ = S[q];                                       \
    _Pragma("unroll")                                                         \
    for (int r_ = 0; r_ < 32; r_++) {                                         \
        if (!(r_ & (m))) {                                                    \
            const int b_ = r_ | (m);                                          \
            const float axr = sr[r_], axi = si[r_];                           \
            const float bxr = sr[b_], bxi = si[b_];                           \
            sr[r_] = cq_ * axr - sq_ * bxr;                                   \
            si[r_] = cq_ * axi - sq_ * bxi;                                   \
            sr[b_] = sq_ * axr + cq_ * bxr;                                   \
            si[b_] = sq_ * axi + cq_ * bxi;                                   \
        }                                                                     \
    }                                                                         \
} while (0)

// RY butterfly on lane bit 0 (qubit 5, layout B) via DPP quad_perm [1,0,3,2]
#define DPP_STAGE() do {                                                      \
    const float cq_ = C[5];                                                   \
    const float ssn_ = (lane & 1) ? S[5] : -S[5];                             \
    _Pragma("unroll")                                                         \
    for (int r_ = 0; r_ < 32; r_++) {                                         \
        const float pr_ = dpp_mov<0xB1>(sr[r_]);                              \
        const float pi_ = dpp_mov<0xB1>(si[r_]);                              \
        sr[r_] = cq_ * sr[r_] + ssn_ * pr_;                                   \
        si[r_] = cq_ * si[r_] + ssn_ * pi_;                                   \
    }                                                                         \
} while (0)

// swizzle: physical = i ^ ((i>>6)&15); both A- and B-side patterns at floor
#define T_A2B() do {                                                          \
    _Pragma("unroll")                                                         \
    for (int r_ = 0; r_ < 32; r_++) {                                         \
        const int i_ = (r_ << 6) | lane;                                      \
        ws[i_ ^ (r_ & 15)] = make_float2(sr[r_], si[r_]);                     \
    }                                                                         \
    __builtin_amdgcn_sched_barrier(0);                                        \
    _Pragma("unroll")                                                         \
    for (int r_ = 0; r_ < 32; r_++) {                                         \
        const float2 v_ = ws[((lane << 5) | r_) ^ ((lane >> 1) & 15)];        \
        sr[r_] = v_.x; si[r_] = v_.y;                                         \
    }                                                                         \
} while (0)

#define T_B2A() do {                                                          \
    _Pragma("unroll")                                                         \
    for (int r_ = 0; r_ < 32; r_++) {                                         \
        ws[((lane << 5) | r_) ^ ((lane >> 1) & 15)] =                         \
            make_float2(sr[r_], si[r_]);                                      \
    }                                                                         \
    __builtin_amdgcn_sched_barrier(0);                                        \
    _Pragma("unroll")                                                         \
    for (int r_ = 0; r_ < 32; r_++) {                                         \
        const float2 v_ = ws[((r_ << 6) | lane) ^ (r_ & 15)];                 \
        sr[r_] = v_.x; si[r_] = v_.y;                                         \
    }                                                                         \
} while (0)

// apply full U (11 RYs): layout A in, layout B out
#define APPLY_CORE() do {                                                     \
    REG_STAGE(0, 16); REG_STAGE(1, 8); REG_STAGE(2, 4);                       \
    REG_STAGE(3, 2);  REG_STAGE(4, 1);                                        \
    T_A2B();                                                                  \
    REG_STAGE(6, 16); REG_STAGE(7, 8); REG_STAGE(8, 4);                       \
    REG_STAGE(9, 2);  REG_STAGE(10, 1);                                       \
    DPP_STAGE();                                                              \
} while (0)

// Pauli X/Y/Z for a register-bit qubit (mask m), output slot q
#define MEASURE_REGBIT(q, m) do {                                             \
    float px_ = 0.f, py_ = 0.f, pz_ = 0.f;                                    \
    _Pragma("unroll")                                                         \
    for (int r_ = 0; r_ < 32; r_++) {                                         \
        const int j_ = r_ ^ (m);                                              \
        px_ += sr[r_] * sr[j_] + si[r_] * si[j_];                             \
        const float imz_ = sr[r_] * si[j_] - si[r_] * sr[j_];                 \
        py_ += (r_ & (m)) ? -imz_ : imz_;                                     \
        const float p2_ = sr[r_] * sr[r_] + si[r_] * si[r_];                  \
        pz_ += (r_ & (m)) ? -p2_ : p2_;                                       \
    }                                                                         \
    px_ = wave_sum(px_); py_ = wave_sum(py_); pz_ = wave_sum(pz_);            \
    if (lane == 0) {                                                          \
        out[3 * (q) + 0] = px_;                                               \
        out[3 * (q) + 1] = py_;                                               \
        out[3 * (q) + 2] = pz_;                                               \
    }                                                                         \
} while (0)

// Pauli X/Y/Z for qubit 5 in layout B (lane bit 0, DPP partner)
#define MEASURE_Q5() do {                                                     \
    float px_ = 0.f, py_ = 0.f, pz_ = 0.f;                                    \
    const int bit_ = lane & 1;                                                \
    _Pragma("unroll")                                                         \
    for (int r_ = 0; r_ < 32; r_++) {                                         \
        const float pr_ = dpp_mov<0xB1>(sr[r_]);                              \
        const float pi_ = dpp_mov<0xB1>(si[r_]);                              \
        px_ += sr[r_] * pr_ + si[r_] * pi_;                                   \
        const float imz_ = sr[r_] * pi_ - si[r_] * pr_;                       \
        py_ += bit_ ? -imz_ : imz_;                                           \
        const float p2_ = sr[r_] * sr[r_] + si[r_] * si[r_];                  \
        pz_ += bit_ ? -p2_ : p2_;                                             \
    }                                                                         \
    px_ = wave_sum(px_); py_ = wave_sum(py_); pz_ = wave_sum(pz_);            \
    if (lane == 0) { out[15] = px_; out[16] = py_; out[17] = pz_; }           \
} while (0)

__global__ __launch_bounds__(256, 1) void quixer_kernel(
    const float* __restrict__ emb,    // [32,512]
    const float* __restrict__ Wang,   // [44,512]
    const float* __restrict__ bang,   // [44]
    const float* __restrict__ qc,     // [3]
    const float* __restrict__ lre,    // [32]
    const float* __restrict__ lim,    // [32]
    const float* __restrict__ ffp,    // [44]
    float* __restrict__ out)          // [33]
{
    __shared__ float2 ex[4][2048];    // 64 KB: LCU exchange + per-wave transpose scratch

    const int tid  = threadIdx.x;
    const int w    = tid >> 6;        // wave id == token id
    const int lane = tid & 63;
    float2* ws = &ex[w][0];           // this wave's private 16KB region

    // ---- Phase A: token angles (11 dots of 512, DPP-reduced) ----
    float C[NQ], S[NQ];
    {
        const float* e = emb + (w << 9);
        float ev[8];
#pragma unroll
        for (int j = 0; j < 8; j++) ev[j] = e[lane + (j << 6)];
        float part[NQ];
#pragma unroll
        for (int q = 0; q < NQ; q++) {
            const float* w0 = Wang + (q << 9);
            const float* w1 = Wang + ((q + 22) << 9);
            float a = 0.f;
#pragma unroll
            for (int j = 0; j < 8; j++) {
                const int d = lane + (j << 6);
                a += ev[j] * (w0[d] + w1[d]);
            }
            part[q] = a;
        }
#pragma unroll
        for (int q = 0; q < NQ; q++) {
            const float phi = wave_sum(part[q]) + bang[q] + bang[q + 22];
            __sincosf(0.5f * phi, &S[q], &C[q]);
        }
    }

    // ---- LCU coefficients ----
    float lr, li;
    {
        float av = 0.f;
        if (lane < 32) {
            const float re = lre[lane], iv = lim[lane];
            av = sqrtf(re * re + iv * iv);
        }
        const float denom = fmaxf(wave_sum(av), 1e-8f);
        lr = lre[w] / denom;
        li = lim[w] / denom;
    }
    const float qc0 = qc[0], qc1 = qc[1], qc2 = qc[2];

    // ---- init: mono = e0 (layout A), acc = qc0*e0 ----
    float sr[32], si[32], ar[32], ai[32];
#pragma unroll
    for (int r = 0; r < 32; r++) { sr[r] = 0.f; si[r] = 0.f; ar[r] = 0.f; ai[r] = 0.f; }
    if (lane == 0) { sr[0] = 1.f; ar[0] = qc0; }

    // ---- QSVT recursion ----
#pragma unroll
    for (int k = 1; k <= 2; k++) {
        float nsq = 0.f;
#pragma unroll
        for (int r = 0; r < 32; r++) nsq += sr[r] * sr[r] + si[r] * si[r];
        nsq = wave_sum(nsq);
        if (sqrtf(nsq) < 1e-8f) {   // faithful small-norm branch
#pragma unroll
            for (int r = 0; r < 32; r++) { sr[r] = 0.f; si[r] = 0.f; }
            if (lane == 0) sr[0] = 1.f;
        }

        APPLY_CORE();   // A -> B
        T_B2A();        // back to layout A

        // exchange: ws[i] = lcu[w] * (U_w mono), then 4-way sum
#pragma unroll
        for (int r = 0; r < 32; r++) {
            const int i = (r << 6) | lane;
            ws[i] = make_float2(lr * sr[r] - li * si[r],
                                lr * si[r] + li * sr[r]);
        }
        __syncthreads();
#pragma unroll
        for (int r = 0; r < 32; r++) {
            const int i = (r << 6) | lane;
            const float2 v0 = ex[0][i], v1 = ex[1][i], v2 = ex[2][i], v3 = ex[3][i];
            sr[r] = v0.x + v1.x + v2.x + v3.x;
            si[r] = v0.y + v1.y + v2.y + v3.y;
        }
        const float qk = (k == 1) ? qc1 : qc2;
#pragma unroll
        for (int r = 0; r < 32; r++) { ar[r] += qk * sr[r]; ai[r] += qk * si[r]; }
        __syncthreads();   // regions reusable (transpose scratch) next iter
    }

    // ---- Phase D: normalize acc (pn cancels except in the 1e-8 check) ----
    const float pn = fmaxf(fabsf(qc0) + fabsf(qc1) + fabsf(qc2), 1e-8f);
    float snsq = 0.f;
#pragma unroll
    for (int r = 0; r < 32; r++) snsq += ar[r] * ar[r] + ai[r] * ai[r];
    snsq = wave_sum(snsq);
    if (sqrtf(snsq) / pn < 1e-8f) {
#pragma unroll
        for (int r = 0; r < 32; r++) { sr[r] = 0.f; si[r] = 0.f; }
        if (lane == 0) sr[0] = 1.f;
    } else {
        const float inv = 1.f / sqrtf(snsq);
#pragma unroll
        for (int r = 0; r < 32; r++) { sr[r] = ar[r] * inv; si[r] = ai[r] * inv; }
    }

    // ---- U_ff ----
#pragma unroll
    for (int q = 0; q < NQ; q++) {
        const float phi = ffp[q] + ffp[q + 22];
        __sincosf(0.5f * phi, &S[q], &C[q]);
    }
    APPLY_CORE();   // ends in layout B

    // ---- measurements: layout B first (q5 DPP, q6..10 reg), then A (q0..4) ----
    switch (w) {
        case 0: MEASURE_REGBIT(8, 4);  break;
        case 1: MEASURE_Q5(); MEASURE_REGBIT(9, 2); break;
        case 2: MEASURE_REGBIT(6, 16); MEASURE_REGBIT(10, 1); break;
        case 3: MEASURE_REGBIT(7, 8);  break;
    }
    T_B2A();        // wave-private; no barrier needed
    switch (w) {
        case 0: MEASURE_REGBIT(0, 16); MEASURE_REGBIT(4, 1); break;
        case 1: MEASURE_REGBIT(1, 8);  break;
        case 2: MEASURE_REGBIT(2, 4);  break;
        case 3: MEASURE_REGBIT(3, 2);  break;
    }
}

extern "C" void kernel_launch(void* const* d_in, const int* in_sizes, int n_in,
                              void* d_out, int out_size, void* d_ws, size_t ws_size,
                              hipStream_t stream) {
    quixer_kernel<<<1, 256, 0, stream>>>(
        (const float*)d_in[0],  // tokens_emb [32,512]
        (const float*)d_in[1],  // W_angles   [44,512]
        (const float*)d_in[2],  // b_angles   [44]
        (const float*)d_in[3],  // qsvt_coeffs[3]
        (const float*)d_in[4],  // lcu_re     [32]
        (const float*)d_in[5],  // lcu_im     [32]
        (const float*)d_in[6],  // ff_params  [44]
        (float*)d_out);         // [33]
}

// Round 4
// 81.132 us; speedup vs baseline: 1.5315x; 1.0117x over previous
//
#include <hip/hip_runtime.h>
#include <math.h>

// QuixerCore on gfx950 — register-resident statevector, v4.
//  * k=1 monomial closed-form: U_t|0> = ⊗_q (c_q, s_q) is REAL -> no butterfly,
//    half-width LDS exchange.
//  * state as float2 ext-vector (re,im): RY coefficients are real and shared,
//    so butterflies lower to v_pk_fma_f32 (2 lanes/instr).
//  * reductions via DPP row_shr/row_bcast; q5 butterfly via DPP quad_perm.
//  * 4 waves = 4 tokens; 4 LDS transposes total (XOR-swizzled, conflict-free).
//
// Layout A: lane L holds sv[r] = state[(r<<6)|L] (qubit q<5 -> r bit 4-q,
//           qubit q in 5..10 -> lane bit 10-q).
// Layout B: lane L holds sv[r] = state[(L<<5)|r] (qubit 6..10 -> r bit 10-q,
//           qubit 5 -> lane bit 0, qubit 0..4 -> lane bits 5..1).

#define NQ 11
typedef float v2f __attribute__((ext_vector_type(2)));

__device__ __forceinline__ v2f splat(float x) { v2f v; v.x = x; v.y = x; return v; }

template<int CTRL>
__device__ __forceinline__ float dpp_mov(float x) {
    return __int_as_float(__builtin_amdgcn_update_dpp(
        0, __float_as_int(x), CTRL, 0xF, 0xF, false));
}

// full-wave sum, uniform result
__device__ __forceinline__ float wave_sum(float v) {
    v += dpp_mov<0x111>(v);   // row_shr:1
    v += dpp_mov<0x112>(v);   // row_shr:2
    v += dpp_mov<0x114>(v);   // row_shr:4
    v += dpp_mov<0x118>(v);   // row_shr:8
    v += dpp_mov<0x142>(v);   // row_bcast:15
    v += dpp_mov<0x143>(v);   // row_bcast:31
    return __int_as_float(__builtin_amdgcn_readlane(__float_as_int(v), 63));
}

// RY butterfly on register-bit mask m (packed re/im)
#define REG_STAGE(q, m) do {                                                  \
    const v2f cq_ = splat(C[q]), sq_ = splat(S[q]);                           \
    _Pragma("unroll")                                                         \
    for (int r_ = 0; r_ < 32; r_++) {                                         \
        if (!(r_ & (m))) {                                                    \
            const int b_ = r_ | (m);                                          \
            const v2f a_ = sv[r_], b2_ = sv[b_];                              \
            sv[r_] = cq_ * a_ - sq_ * b2_;                                    \
            sv[b_] = sq_ * a_ + cq_ * b2_;                                    \
        }                                                                     \
    }                                                                         \
} while (0)

// RY butterfly on lane bit 0 (qubit 5, layout B) via DPP quad_perm [1,0,3,2]
#define DPP_STAGE() do {                                                      \
    const v2f cq_ = splat(C[5]);                                              \
    const v2f ssn_ = splat((lane & 1) ? S[5] : -S[5]);                        \
    _Pragma("unroll")                                                         \
    for (int r_ = 0; r_ < 32; r_++) {                                         \
        v2f p_;                                                               \
        p_.x = dpp_mov<0xB1>(sv[r_].x);                                       \
        p_.y = dpp_mov<0xB1>(sv[r_].y);                                       \
        sv[r_] = cq_ * sv[r_] + ssn_ * p_;                                    \
    }                                                                         \
} while (0)

// swizzle: physical = i ^ ((i>>6)&15); conflict-free both directions
#define T_A2B() do {                                                          \
    _Pragma("unroll")                                                         \
    for (int r_ = 0; r_ < 32; r_++) {                                         \
        const int i_ = (r_ << 6) | lane;                                      \
        ws[i_ ^ (r_ & 15)] = make_float2(sv[r_].x, sv[r_].y);                 \
    }                                                                         \
    __builtin_amdgcn_sched_barrier(0);                                        \
    _Pragma("unroll")                                                         \
    for (int r_ = 0; r_ < 32; r_++) {                                         \
        const float2 v_ = ws[((lane << 5) | r_) ^ ((lane >> 1) & 15)];        \
        sv[r_].x = v_.x; sv[r_].y = v_.y;                                     \
    }                                                                         \
} while (0)

#define T_B2A() do {                                                          \
    _Pragma("unroll")                                                         \
    for (int r_ = 0; r_ < 32; r_++) {                                         \
        ws[((lane << 5) | r_) ^ ((lane >> 1) & 15)] =                         \
            make_float2(sv[r_].x, sv[r_].y);                                  \
    }                                                                         \
    __builtin_amdgcn_sched_barrier(0);                                        \
    _Pragma("unroll")                                                         \
    for (int r_ = 0; r_ < 32; r_++) {                                         \
        const float2 v_ = ws[((r_ << 6) | lane) ^ (r_ & 15)];                 \
        sv[r_].x = v_.x; sv[r_].y = v_.y;                                     \
    }                                                                         \
} while (0)

// full U (11 RYs): layout A in -> layout B out
#define APPLY_CORE() do {                                                     \
    REG_STAGE(0, 16); REG_STAGE(1, 8); REG_STAGE(2, 4);                       \
    REG_STAGE(3, 2);  REG_STAGE(4, 1);                                        \
    T_A2B();                                                                  \
    REG_STAGE(6, 16); REG_STAGE(7, 8); REG_STAGE(8, 4);                       \
    REG_STAGE(9, 2);  REG_STAGE(10, 1);                                       \
    DPP_STAGE();                                                              \
} while (0)

#define MEASURE_REGBIT(q, m) do {                                             \
    float px_ = 0.f, py_ = 0.f, pz_ = 0.f;                                    \
    _Pragma("unroll")                                                         \
    for (int r_ = 0; r_ < 32; r_++) {                                         \
        const int j_ = r_ ^ (m);                                              \
        px_ += sv[r_].x * sv[j_].x + sv[r_].y * sv[j_].y;                     \
        const float imz_ = sv[r_].x * sv[j_].y - sv[r_].y * sv[j_].x;         \
        py_ += (r_ & (m)) ? -imz_ : imz_;                                     \
        const float p2_ = sv[r_].x * sv[r_].x + sv[r_].y * sv[r_].y;          \
        pz_ += (r_ & (m)) ? -p2_ : p2_;                                       \
    }                                                                         \
    px_ = wave_sum(px_); py_ = wave_sum(py_); pz_ = wave_sum(pz_);            \
    if (lane == 0) {                                                          \
        out[3 * (q) + 0] = px_;                                               \
        out[3 * (q) + 1] = py_;                                               \
        out[3 * (q) + 2] = pz_;                                               \
    }                                                                         \
} while (0)

#define MEASURE_Q5() do {                                                     \
    float px_ = 0.f, py_ = 0.f, pz_ = 0.f;                                    \
    const int bit_ = lane & 1;                                                \
    _Pragma("unroll")                                                         \
    for (int r_ = 0; r_ < 32; r_++) {                                         \
        const float pr_ = dpp_mov<0xB1>(sv[r_].x);                            \
        const float pi_ = dpp_mov<0xB1>(sv[r_].y);                            \
        px_ += sv[r_].x * pr_ + sv[r_].y * pi_;                               \
        const float imz_ = sv[r_].x * pi_ - sv[r_].y * pr_;                   \
        py_ += bit_ ? -imz_ : imz_;                                           \
        const float p2_ = sv[r_].x * sv[r_].x + sv[r_].y * sv[r_].y;          \
        pz_ += bit_ ? -p2_ : p2_;                                             \
    }                                                                         \
    px_ = wave_sum(px_); py_ = wave_sum(py_); pz_ = wave_sum(pz_);            \
    if (lane == 0) { out[15] = px_; out[16] = py_; out[17] = pz_; }           \
} while (0)

__global__ __launch_bounds__(256, 1) void quixer_kernel(
    const float* __restrict__ emb,    // [32,512]
    const float* __restrict__ Wang,   // [44,512]
    const float* __restrict__ bang,   // [44]
    const float* __restrict__ qc,     // [3]
    const float* __restrict__ lre,    // [32]
    const float* __restrict__ lim,    // [32]
    const float* __restrict__ ffp,    // [44]
    float* __restrict__ out)          // [33]
{
    __shared__ float2 ex[4][2048];    // 64 KB: exchange + per-wave transpose scratch

    const int tid  = threadIdx.x;
    const int w    = tid >> 6;        // wave id == token id
    const int lane = tid & 63;
    float2* ws = &ex[w][0];           // this wave's private 16 KB region

    // ---- Phase A: token angles (11 dots of 512, DPP-reduced) ----
    float C[NQ], S[NQ];
    {
        const float* e = emb + (w << 9);
        float ev[8];
#pragma unroll
        for (int j = 0; j < 8; j++) ev[j] = e[lane + (j << 6)];
        float part[NQ];
#pragma unroll
        for (int q = 0; q < NQ; q++) {
            const float* w0 = Wang + (q << 9);
            const float* w1 = Wang + ((q + 22) << 9);
            float a = 0.f;
#pragma unroll
            for (int j = 0; j < 8; j++) {
                const int d = lane + (j << 6);
                a += ev[j] * (w0[d] + w1[d]);
            }
            part[q] = a;
        }
#pragma unroll
        for (int q = 0; q < NQ; q++) {
            const float phi = wave_sum(part[q]) + bang[q] + bang[q + 22];
            __sincosf(0.5f * phi, &S[q], &C[q]);
        }
    }

    // ---- LCU coefficients (all 4, every wave) ----
    float lrv[4], liv[4];
    {
        float av = 0.f;
        if (lane < 32) {
            const float re = lre[lane], iv = lim[lane];
            av = sqrtf(re * re + iv * iv);
        }
        const float denom = fmaxf(wave_sum(av), 1e-8f);
#pragma unroll
        for (int t = 0; t < 4; t++) { lrv[t] = lre[t] / denom; liv[t] = lim[t] / denom; }
    }
    const float qc0 = qc[0], qc1 = qc[1], qc2 = qc[2];

    v2f sv[32], av[32];
#pragma unroll
    for (int r = 0; r < 32; r++) { av[r].x = 0.f; av[r].y = 0.f; }
    if (lane == 0) av[0].x = qc0;     // acc = qc0 * e0

    // ---- k=1: mono=e0, U_t|0> closed-form (REAL), half-width exchange ----
    // ||e0|| = 1 so the small-norm branch cannot fire (faithful skip).
    {
        float lp = 1.f;
#pragma unroll
        for (int q = 5; q < 11; q++)
            lp *= ((lane >> (10 - q)) & 1) ? S[q] : C[q];
        float t[32];
        t[0] = lp;
#pragma unroll
        for (int q = 4; q >= 0; q--) {
            const int m = 1 << (4 - q);
#pragma unroll
            for (int j = 0; j < 32; j++) {
                if (j < m) {
                    t[j | m] = t[j] * S[q];
                    t[j]     = t[j] * C[q];
                }
            }
        }
        float* wsf = (float*)ws;
#pragma unroll
        for (int r = 0; r < 32; r++) wsf[(r << 6) | lane] = t[r];
        __syncthreads();
        const float* exf = (const float*)(&ex[0][0]);
#pragma unroll
        for (int r = 0; r < 32; r++) {
            const int i = (r << 6) | lane;
            const float v0 = exf[i], v1 = exf[4096 + i];
            const float v2 = exf[8192 + i], v3 = exf[12288 + i];
            v2f m0;
            m0.x = lrv[0]*v0 + lrv[1]*v1 + lrv[2]*v2 + lrv[3]*v3;
            m0.y = liv[0]*v0 + liv[1]*v1 + liv[2]*v2 + liv[3]*v3;
            sv[r] = m0;
            av[r] += splat(qc1) * m0;
        }
        __syncthreads();   // regions become transpose scratch next
    }

    // ---- k=2: faithful small-norm check, full APPLY, complex exchange ----
    {
        float nsq = 0.f;
#pragma unroll
        for (int r = 0; r < 32; r++) nsq += sv[r].x * sv[r].x + sv[r].y * sv[r].y;
        nsq = wave_sum(nsq);
        if (sqrtf(nsq) < 1e-8f) {
#pragma unroll
            for (int r = 0; r < 32; r++) { sv[r].x = 0.f; sv[r].y = 0.f; }
            if (lane == 0) sv[0].x = 1.f;
        }

        APPLY_CORE();   // A -> B
        T_B2A();        // back to A

        const float lr = lrv[w], li = liv[w];
#pragma unroll
        for (int r = 0; r < 32; r++) {
            const int i = (r << 6) | lane;
            ws[i] = make_float2(lr * sv[r].x - li * sv[r].y,
                                lr * sv[r].y + li * sv[r].x);
        }
        __syncthreads();
#pragma unroll
        for (int r = 0; r < 32; r++) {
            const int i = (r << 6) | lane;
            const float2 v0 = ex[0][i], v1 = ex[1][i], v2 = ex[2][i], v3 = ex[3][i];
            v2f m0;
            m0.x = v0.x + v1.x + v2.x + v3.x;
            m0.y = v0.y + v1.y + v2.y + v3.y;
            sv[r] = m0;
            av[r] += splat(qc2) * m0;
        }
        __syncthreads();   // regions reusable (U_ff transpose scratch)
    }

    // ---- Phase D: normalize acc (poly_norm cancels except in 1e-8 check) ----
    {
        const float pn = fmaxf(fabsf(qc0) + fabsf(qc1) + fabsf(qc2), 1e-8f);
        float snsq = 0.f;
#pragma unroll
        for (int r = 0; r < 32; r++) snsq += av[r].x * av[r].x + av[r].y * av[r].y;
        snsq = wave_sum(snsq);
        if (sqrtf(snsq) / pn < 1e-8f) {
#pragma unroll
            for (int r = 0; r < 32; r++) { sv[r].x = 0.f; sv[r].y = 0.f; }
            if (lane == 0) sv[0].x = 1.f;
        } else {
            const v2f inv = splat(1.f / sqrtf(snsq));
#pragma unroll
            for (int r = 0; r < 32; r++) sv[r] = av[r] * inv;
        }
    }

    // ---- U_ff ----
#pragma unroll
    for (int q = 0; q < NQ; q++) {
        const float phi = ffp[q] + ffp[q + 22];
        __sincosf(0.5f * phi, &S[q], &C[q]);
    }
    APPLY_CORE();   // ends in layout B

    // ---- measurements: layout B (q5 DPP, q6..10 reg), then A (q0..4) ----
    switch (w) {
        case 0: MEASURE_REGBIT(8, 4);  break;
        case 1: MEASURE_Q5(); MEASURE_REGBIT(9, 2); break;
        case 2: MEASURE_REGBIT(6, 16); MEASURE_REGBIT(10, 1); break;
        case 3: MEASURE_REGBIT(7, 8);  break;
    }
    T_B2A();        // wave-private; no barrier needed
    switch (w) {
        case 0: MEASURE_REGBIT(0, 16); MEASURE_REGBIT(4, 1); break;
        case 1: MEASURE_REGBIT(1, 8);  break;
        case 2: MEASURE_REGBIT(2, 4);  break;
        case 3: MEASURE_REGBIT(3, 2);  break;
    }
}

extern "C" void kernel_launch(void* const* d_in, const int* in_sizes, int n_in,
                              void* d_out, int out_size, void* d_ws, size_t ws_size,
                              hipStream_t stream) {
    quixer_kernel<<<1, 256, 0, stream>>>(
        (const float*)d_in[0],  // tokens_emb [32,512]
        (const float*)d_in[1],  // W_angles   [44,512]
        (const float*)d_in[2],  // b_angles   [44]
        (const float*)d_in[3],  // qsvt_coeffs[3]
        (const float*)d_in[4],  // lcu_re     [32]
        (const float*)d_in[5],  // lcu_im     [32]
        (const float*)d_in[6],  // ff_params  [44]
        (float*)d_out);         // [33]
}

// Round 5
// 78.472 us; speedup vs baseline: 1.5834x; 1.0339x over previous
//
#include <hip/hip_runtime.h>
#include <math.h>

// QuixerCore on gfx950 — register-resident statevector, v5 (latency-focused).
//  * All global loads hoisted to kernel entry (float4 for emb/Wang; uniform
//    scalar loads for bang/qc/ffp); U_ff sincos computed in load shadow.
//  * k=1 closed-form (U_t|0> real, tensor product of (c,s)).
//  * Butterflies: reg-bit stages (packed f32) + one XOR-swizzled LDS
//    transpose per apply + DPP quad_perm for qubit 5.
//  * Reductions: DPP row_shr/row_bcast + readlane. Zero ds_bpermute.
//
// Layout A: lane L holds sv[r] = state[(r<<6)|L] (qubit q<5 -> r bit 4-q,
//           qubit 5..10 -> lane bit 10-q).
// Layout B: lane L holds sv[r] = state[(L<<5)|r] (qubit 6..10 -> r bit 10-q,
//           qubit 5 -> lane bit 0, qubit 0..4 -> lane bits 5..1).

#define NQ 11
typedef float v2f __attribute__((ext_vector_type(2)));

__device__ __forceinline__ v2f splat(float x) { v2f v; v.x = x; v.y = x; return v; }

template<int CTRL>
__device__ __forceinline__ float dpp_mov(float x) {
    return __int_as_float(__builtin_amdgcn_update_dpp(
        0, __float_as_int(x), CTRL, 0xF, 0xF, false));
}

// full-wave sum, uniform result
__device__ __forceinline__ float wave_sum(float v) {
    v += dpp_mov<0x111>(v);   // row_shr:1
    v += dpp_mov<0x112>(v);   // row_shr:2
    v += dpp_mov<0x114>(v);   // row_shr:4
    v += dpp_mov<0x118>(v);   // row_shr:8
    v += dpp_mov<0x142>(v);   // row_bcast:15
    v += dpp_mov<0x143>(v);   // row_bcast:31
    return __int_as_float(__builtin_amdgcn_readlane(__float_as_int(v), 63));
}

// RY butterfly on register-bit mask m with coefficient arrays CC/SS
#define REG_STAGE(CC, SS, q, m) do {                                          \
    const v2f cq_ = splat(CC[q]), sq_ = splat(SS[q]);                         \
    _Pragma("unroll")                                                         \
    for (int r_ = 0; r_ < 32; r_++) {                                         \
        if (!(r_ & (m))) {                                                    \
            const int b_ = r_ | (m);                                          \
            const v2f a_ = sv[r_], b2_ = sv[b_];                              \
            sv[r_] = cq_ * a_ - sq_ * b2_;                                    \
            sv[b_] = sq_ * a_ + cq_ * b2_;                                    \
        }                                                                     \
    }                                                                         \
} while (0)

// RY butterfly on lane bit 0 (qubit 5, layout B) via DPP quad_perm [1,0,3,2]
#define DPP_STAGE(CC, SS) do {                                                \
    const v2f cq_ = splat(CC[5]);                                             \
    const v2f ssn_ = splat((lane & 1) ? SS[5] : -SS[5]);                      \
    _Pragma("unroll")                                                         \
    for (int r_ = 0; r_ < 32; r_++) {                                         \
        v2f p_;                                                               \
        p_.x = dpp_mov<0xB1>(sv[r_].x);                                       \
        p_.y = dpp_mov<0xB1>(sv[r_].y);                                       \
        sv[r_] = cq_ * sv[r_] + ssn_ * p_;                                    \
    }                                                                         \
} while (0)

// transposes, XOR swizzle physical = i ^ ((i>>6)&15): conflict-free both ways.
// LDS same-address aliasing forces write->read order; no sched pinning.
#define T_A2B() do {                                                          \
    _Pragma("unroll")                                                         \
    for (int r_ = 0; r_ < 32; r_++) {                                         \
        const int i_ = (r_ << 6) | lane;                                      \
        ws[i_ ^ (r_ & 15)] = make_float2(sv[r_].x, sv[r_].y);                 \
    }                                                                         \
    _Pragma("unroll")                                                         \
    for (int r_ = 0; r_ < 32; r_++) {                                         \
        const float2 v_ = ws[((lane << 5) | r_) ^ ((lane >> 1) & 15)];        \
        sv[r_].x = v_.x; sv[r_].y = v_.y;                                     \
    }                                                                         \
} while (0)

#define T_B2A() do {                                                          \
    _Pragma("unroll")                                                         \
    for (int r_ = 0; r_ < 32; r_++) {                                         \
        ws[((lane << 5) | r_) ^ ((lane >> 1) & 15)] =                         \
            make_float2(sv[r_].x, sv[r_].y);                                  \
    }                                                                         \
    _Pragma("unroll")                                                         \
    for (int r_ = 0; r_ < 32; r_++) {                                         \
        const float2 v_ = ws[((r_ << 6) | lane) ^ (r_ & 15)];                 \
        sv[r_].x = v_.x; sv[r_].y = v_.y;                                     \
    }                                                                         \
} while (0)

// full U (11 RYs): layout A in -> layout B out
#define APPLY_CORE(CC, SS) do {                                               \
    REG_STAGE(CC, SS, 0, 16); REG_STAGE(CC, SS, 1, 8);                        \
    REG_STAGE(CC, SS, 2, 4);  REG_STAGE(CC, SS, 3, 2);                        \
    REG_STAGE(CC, SS, 4, 1);                                                  \
    T_A2B();                                                                  \
    REG_STAGE(CC, SS, 6, 16); REG_STAGE(CC, SS, 7, 8);                        \
    REG_STAGE(CC, SS, 8, 4);  REG_STAGE(CC, SS, 9, 2);                        \
    REG_STAGE(CC, SS, 10, 1);                                                 \
    DPP_STAGE(CC, SS);                                                        \
} while (0)

#define MEASURE_REGBIT(q, m) do {                                             \
    float px_ = 0.f, py_ = 0.f, pz_ = 0.f;                                    \
    _Pragma("unroll")                                                         \
    for (int r_ = 0; r_ < 32; r_++) {                                         \
        const int j_ = r_ ^ (m);                                              \
        px_ += sv[r_].x * sv[j_].x + sv[r_].y * sv[j_].y;                     \
        const float imz_ = sv[r_].x * sv[j_].y - sv[r_].y * sv[j_].x;         \
        py_ += (r_ & (m)) ? -imz_ : imz_;                                     \
        const float p2_ = sv[r_].x * sv[r_].x + sv[r_].y * sv[r_].y;          \
        pz_ += (r_ & (m)) ? -p2_ : p2_;                                       \
    }                                                                         \
    px_ = wave_sum(px_); py_ = wave_sum(py_); pz_ = wave_sum(pz_);            \
    if (lane == 0) {                                                          \
        out[3 * (q) + 0] = px_;                                               \
        out[3 * (q) + 1] = py_;                                               \
        out[3 * (q) + 2] = pz_;                                               \
    }                                                                         \
} while (0)

#define MEASURE_Q5() do {                                                     \
    float px_ = 0.f, py_ = 0.f, pz_ = 0.f;                                    \
    const int bit_ = lane & 1;                                                \
    _Pragma("unroll")                                                         \
    for (int r_ = 0; r_ < 32; r_++) {                                         \
        const float pr_ = dpp_mov<0xB1>(sv[r_].x);                            \
        const float pi_ = dpp_mov<0xB1>(sv[r_].y);                            \
        px_ += sv[r_].x * pr_ + sv[r_].y * pi_;                               \
        const float imz_ = sv[r_].x * pi_ - sv[r_].y * pr_;                   \
        py_ += bit_ ? -imz_ : imz_;                                           \
        const float p2_ = sv[r_].x * sv[r_].x + sv[r_].y * sv[r_].y;          \
        pz_ += bit_ ? -p2_ : p2_;                                             \
    }                                                                         \
    px_ = wave_sum(px_); py_ = wave_sum(py_); pz_ = wave_sum(pz_);            \
    if (lane == 0) { out[15] = px_; out[16] = py_; out[17] = pz_; }           \
} while (0)

__global__ __launch_bounds__(256, 1) void quixer_kernel(
    const float* __restrict__ emb,    // [32,512]
    const float* __restrict__ Wang,   // [44,512]
    const float* __restrict__ bang,   // [44]
    const float* __restrict__ qc,     // [3]
    const float* __restrict__ lre,    // [32]
    const float* __restrict__ lim,    // [32]
    const float* __restrict__ ffp,    // [44]
    float* __restrict__ out)          // [33]
{
    __shared__ float2 ex[4][2048];    // 64 KB: exchange + per-wave transpose scratch

    const int tid  = threadIdx.x;
    const int w    = tid >> 6;        // wave id == token id
    const int lane = tid & 63;
    float2* ws = &ex[w][0];           // this wave's private 16 KB region

    // ======== Front-loaded global reads (everything, immediately) ========
    const float4* e4 = reinterpret_cast<const float4*>(emb + (w << 9));
    const float4 ev0 = e4[lane], ev1 = e4[lane + 64];

    float4 wa0[NQ], wa1[NQ], wb0[NQ], wb1[NQ];
#pragma unroll
    for (int q = 0; q < NQ; q++) {
        const float4* w04 = reinterpret_cast<const float4*>(Wang + (q << 9));
        const float4* w14 = reinterpret_cast<const float4*>(Wang + ((q + 22) << 9));
        wa0[q] = w04[lane];      wa1[q] = w04[lane + 64];
        wb0[q] = w14[lane];      wb1[q] = w14[lane + 64];
    }
    const float qc0 = qc[0], qc1 = qc[1], qc2 = qc[2];
    float relv = 0.f, imlv = 0.f;
    if (lane < 32) { relv = lre[lane]; imlv = lim[lane]; }

    // uniform (SMEM-path) small arrays; U_ff sincos early, in load shadow
    float fC[NQ], fS[NQ], bsum[NQ];
#pragma unroll
    for (int q = 0; q < NQ; q++) {
        bsum[q] = bang[q] + bang[q + 22];
        const float fphi = ffp[q] + ffp[q + 22];
        __sincosf(0.5f * fphi, &fS[q], &fC[q]);
    }

    // ======== Phase A: angles + LCU normalization (interleaved DPP sums) ====
    float C[NQ], S[NQ];
    {
        float part[NQ];
#pragma unroll
        for (int q = 0; q < NQ; q++) {
            const float4 a0 = wa0[q], a1 = wa1[q], b0 = wb0[q], b1 = wb1[q];
            part[q] = ev0.x * (a0.x + b0.x) + ev0.y * (a0.y + b0.y)
                    + ev0.z * (a0.z + b0.z) + ev0.w * (a0.w + b0.w)
                    + ev1.x * (a1.x + b1.x) + ev1.y * (a1.y + b1.y)
                    + ev1.z * (a1.z + b1.z) + ev1.w * (a1.w + b1.w);
        }
#pragma unroll
        for (int q = 0; q < NQ; q++) {
            const float phi = wave_sum(part[q]) + bsum[q];
            __sincosf(0.5f * phi, &S[q], &C[q]);
        }
    }
    float lrv[4], liv[4];
    {
        const float avn = sqrtf(relv * relv + imlv * imlv);
        const float denom = fmaxf(wave_sum(avn), 1e-8f);
#pragma unroll
        for (int t = 0; t < 4; t++) { lrv[t] = lre[t] / denom; liv[t] = lim[t] / denom; }
    }

    v2f sv[32], av[32];

    // ---- k=1: mono=e0, U_t|0> closed-form (REAL), half-width exchange ----
    // ||e0|| = 1 exactly, so the small-norm branch cannot fire (faithful skip).
    {
        float lp = 1.f;
#pragma unroll
        for (int q = 5; q < 11; q++)
            lp *= ((lane >> (10 - q)) & 1) ? S[q] : C[q];
        float t[32];
        t[0] = lp;
#pragma unroll
        for (int q = 4; q >= 0; q--) {
            const int m = 1 << (4 - q);
#pragma unroll
            for (int j = 0; j < 32; j++) {
                if (j < m) {
                    t[j | m] = t[j] * S[q];
                    t[j]     = t[j] * C[q];
                }
            }
        }
        float* wsf = (float*)ws;
#pragma unroll
        for (int r = 0; r < 32; r++) wsf[(r << 6) | lane] = t[r];
        __syncthreads();
        const float* exf = (const float*)(&ex[0][0]);
#pragma unroll
        for (int r = 0; r < 32; r++) {
            const int i = (r << 6) | lane;
            const float v0 = exf[i], v1 = exf[4096 + i];
            const float v2 = exf[8192 + i], v3 = exf[12288 + i];
            v2f m0;
            m0.x = lrv[0]*v0 + lrv[1]*v1 + lrv[2]*v2 + lrv[3]*v3;
            m0.y = liv[0]*v0 + liv[1]*v1 + liv[2]*v2 + liv[3]*v3;
            sv[r] = m0;
            av[r] = splat(qc1) * m0;         // acc = qc1*m1 (qc0*e0 added below)
        }
        if (lane == 0) av[0].x += qc0;
        __syncthreads();   // regions become transpose scratch next
    }

    // ---- k=2: faithful small-norm check, full APPLY, complex exchange ----
    {
        float nsq = 0.f;
#pragma unroll
        for (int r = 0; r < 32; r++) nsq += sv[r].x * sv[r].x + sv[r].y * sv[r].y;
        nsq = wave_sum(nsq);
        if (sqrtf(nsq) < 1e-8f) {
#pragma unroll
            for (int r = 0; r < 32; r++) { sv[r].x = 0.f; sv[r].y = 0.f; }
            if (lane == 0) sv[0].x = 1.f;
        }

        APPLY_CORE(C, S);   // A -> B
        T_B2A();            // back to A

        const float lr = lrv[w], li = liv[w];
#pragma unroll
        for (int r = 0; r < 32; r++) {
            const int i = (r << 6) | lane;
            ws[i] = make_float2(lr * sv[r].x - li * sv[r].y,
                                lr * sv[r].y + li * sv[r].x);
        }
        __syncthreads();
#pragma unroll
        for (int r = 0; r < 32; r++) {
            const int i = (r << 6) | lane;
            const float2 v0 = ex[0][i], v1 = ex[1][i], v2 = ex[2][i], v3 = ex[3][i];
            v2f m0;
            m0.x = v0.x + v1.x + v2.x + v3.x;
            m0.y = v0.y + v1.y + v2.y + v3.y;
            sv[r] = m0;
            av[r] += splat(qc2) * m0;
        }
        __syncthreads();   // regions reusable (U_ff transpose scratch)
    }

    // ---- Phase D: normalize acc (poly_norm cancels except in 1e-8 check) ----
    {
        const float pn = fmaxf(fabsf(qc0) + fabsf(qc1) + fabsf(qc2), 1e-8f);
        float snsq = 0.f;
#pragma unroll
        for (int r = 0; r < 32; r++) snsq += av[r].x * av[r].x + av[r].y * av[r].y;
        snsq = wave_sum(snsq);
        if (sqrtf(snsq) / pn < 1e-8f) {
#pragma unroll
            for (int r = 0; r < 32; r++) { sv[r].x = 0.f; sv[r].y = 0.f; }
            if (lane == 0) sv[0].x = 1.f;
        } else {
            const v2f inv = splat(1.f / sqrtf(snsq));
#pragma unroll
            for (int r = 0; r < 32; r++) sv[r] = av[r] * inv;
        }
    }

    // ---- U_ff (coefficients precomputed at kernel entry) ----
    APPLY_CORE(fC, fS);   // ends in layout B

    // ---- measurements: layout B (q5 DPP, q6..10 reg), then A (q0..4) ----
    switch (w) {
        case 0: MEASURE_REGBIT(8, 4);  break;
        case 1: MEASURE_Q5(); MEASURE_REGBIT(9, 2); break;
        case 2: MEASURE_REGBIT(6, 16); MEASURE_REGBIT(10, 1); break;
        case 3: MEASURE_REGBIT(7, 8);  break;
    }
    T_B2A();        // wave-private; no barrier needed
    switch (w) {
        case 0: MEASURE_REGBIT(0, 16); MEASURE_REGBIT(4, 1); break;
        case 1: MEASURE_REGBIT(1, 8);  break;
        case 2: MEASURE_REGBIT(2, 4);  break;
        case 3: MEASURE_REGBIT(3, 2);  break;
    }
}

extern "C" void kernel_launch(void* const* d_in, const int* in_sizes, int n_in,
                              void* d_out, int out_size, void* d_ws, size_t ws_size,
                              hipStream_t stream) {
    quixer_kernel<<<1, 256, 0, stream>>>(
        (const float*)d_in[0],  // tokens_emb [32,512]
        (const float*)d_in[1],  // W_angles   [44,512]
        (const float*)d_in[2],  // b_angles   [44]
        (const float*)d_in[3],  // qsvt_coeffs[3]
        (const float*)d_in[4],  // lcu_re     [32]
        (const float*)d_in[5],  // lcu_im     [32]
        (const float*)d_in[6],  // ff_params  [44]
        (float*)d_out);         // [33]
}